// Round 9
// baseline (287.805 us; speedup 1.0000x reference)
//
#include <hip/hip_runtime.h>

#define NPG 100     // nodes per graph
#define HF 64       // hidden width
#define NROW 128    // node rows padded to 4 x 32 tiles
#define ST 72       // Trm row stride (bf16): 64 + 8 pad
#define SAT 136     // Tc row stride (bf16): 128 + 8 pad
#define CMW 28      // count-matrix words per row (112 u8 cols)

typedef float  f4   __attribute__((ext_vector_type(4)));
typedef float  f16v __attribute__((ext_vector_type(16)));
typedef short  bf8  __attribute__((ext_vector_type(8)));

#define SZ_TC  (HF * SAT * 2)         // 17408
#define SZ_TRM (NROW * ST * 2)        // 18432
#define OFF_TC0  0
#define OFF_TRM0 SZ_TC                // 17408
#define OFF_TC1  (OFF_TRM0 + SZ_TRM)  // 35840
#define OFF_TRM1 (OFF_TC1 + SZ_TC)    // 53248
#define OFF_CM   0                    // u8 counts [128][28 u32] = 14336, overlays Tc0 (setup)
#define OFF_MISC (OFF_TRM1 + SZ_TRM)  // 71680
#define SMEM_BYTES (OFF_MISC + 1280)  // 72960 -> 2 blocks/CU (145920 < 163840)

// bf16 weight workspace (d_ws), layout Wt[k5][fo][fi]:
//   W1t [5][64][16] @ 0  (fi zero-padded 3->16)
//   W2t [5][64][64] @ 5120
//   W3t [5][64][64] @ 25600
#define WT_TOTAL 46080

__device__ __forceinline__ unsigned short f2bf(float f) {
    unsigned u = __float_as_uint(f);
    u += 0x7fffu + ((u >> 16) & 1u);   // round-to-nearest-even
    return (unsigned short)(u >> 16);
}
__device__ __forceinline__ float bf2f(unsigned short h) {
    return __uint_as_float(((unsigned)h) << 16);
}
__device__ __forceinline__ f16v zerov16() {
    f16v z;
    #pragma unroll
    for (int i = 0; i < 16; i++) z[i] = 0.f;
    return z;
}

__global__ void wconv(const float* __restrict__ W1, const float* __restrict__ W2,
                      const float* __restrict__ W3, unsigned short* __restrict__ ws)
{
    int idx = blockIdx.x * 256 + threadIdx.x;
    if (idx >= WT_TOTAL) return;
    float v;
    if (idx < 5120) {
        int k5 = idx >> 10, rem = idx & 1023, fo = rem >> 4, fi = rem & 15;
        v = (fi < 3) ? W1[(k5 * 3 + fi) * HF + fo] : 0.f;
    } else if (idx < 25600) {
        int j = idx - 5120;
        int k5 = j >> 12, rem = j & 4095, fo = rem >> 6, fi = rem & 63;
        v = W2[(k5 * HF + fi) * HF + fo];
    } else {
        int j = idx - 25600;
        int k5 = j >> 12, rem = j & 4095, fo = rem >> 6, fi = rem & 63;
        v = W3[(k5 * HF + fi) * HF + fo];
    }
    ws[idx] = f2bf(v);
}

// One block per graph, 256 threads = 4 waves, 2 blocks/CU.
// A-hat fragments in registers (af[2][7], built once from u8 count matrix).
// PING-PONG dual-orientation T (Tc = T^T for LHAT B b128; Trm for TW A b128):
// stage s reads T_{s-1} from buf A (bfr + TW(s-1) share the read phase), writes
// T_s to buf B, ONE barrier, swap. 5 barriers/layer (was 10).
// LHAT: C[np][fo] = sum_n Ahat[np][n] * T[n][fo]  (A=af regs, B=Tc rows b128)
// TW:   O[np][fo] += sum_fi T[np][fi] * Wt[fo][fi] (A=Trm rows b128, B=Wt b128)
// C/D: col = lane&31, row = (r&3)+8*(r>>2)+4*(lane>>5)
// Cheb prev/old in packed-bf16 regs; layer T0's prev carried from epilogue regs.
// (256,2): R6 lesson — min-waves=3 caps VGPR at ~84 and spills catastrophically.
__launch_bounds__(256, 2)
__global__ void chebpp(const float* __restrict__ x, const int* __restrict__ ei,
                       const float* __restrict__ lambda_max,
                       const unsigned short* __restrict__ Wt,
                       const float* __restrict__ b1, const float* __restrict__ b2,
                       const float* __restrict__ b3,
                       const float* __restrict__ bng, const float* __restrict__ bnb,
                       const float* __restrict__ bnm, const float* __restrict__ bnv,
                       const float* __restrict__ fc1w, const float* __restrict__ fc1b,
                       const float* __restrict__ fc2w, const float* __restrict__ fc2b,
                       float* __restrict__ out, int E_total, int epg)
{
    extern __shared__ char sm[];
    const int tid = threadIdx.x;
    const int g = blockIdx.x;
    const int ebase = g * epg, nbase = g * NPG;
    const int wg = tid >> 6, lane = tid & 63;
    const int l31 = lane & 31, hh = lane >> 5;
    const int ht  = wg & 1;          // f-tile: cols 32*ht..+31
    const int Mt0 = (wg >> 1) * 2;   // n'-tile pair base
    const int fo  = ht * 32 + l31;

    unsigned* Cm  = (unsigned*)(sm + OFF_CM);
    float* dis    = (float*)(sm + OFF_MISC);          // 448 B (112 entries)
    float* pool   = (float*)(sm + OFF_MISC + 448);    // 256 B
    float* gvn    = (float*)(sm + OFF_MISC + 704);    // 256 B
    float* zf     = (float*)(sm + OFF_MISC + 960);    // 128 B
    float* logits = (float*)(sm + OFF_MISC + 1088);   // 64 B
    float* lsep   = (float*)(sm + OFF_MISC + 1152);

    const float lam = lambda_max[g];
    const float two_l = 2.0f / lam;
    const float cl = two_l - 1.0f;

    // ---------------- u8 count matrix + dis ----------------
    for (int i = tid; i < (NROW * CMW) / 4; i += 256)
        ((f4*)Cm)[i] = (f4){0.f, 0.f, 0.f, 0.f};
    __syncthreads();
    for (int e = tid; e < epg; e += 256) {
        int r = ei[ebase + e] - nbase;
        int c = ei[E_total + ebase + e] - nbase;
        atomicAdd(&Cm[r * CMW + (c >> 2)], 1u << (8 * (c & 3)));
    }
    __syncthreads();
    if (tid < 112) {
        float dv = 0.f;
        if (tid < NPG) {
            unsigned s = 0;
            #pragma unroll
            for (int w = 0; w < CMW; w++) {
                unsigned u = Cm[tid * CMW + w];
                s += (u & 255) + ((u >> 8) & 255) + ((u >> 16) & 255) + (u >> 24);
            }
            dv = s > 0 ? rsqrtf((float)s) : 0.f;
        }
        dis[tid] = dv;
    }
    __syncthreads();

    // ---------------- A-hat fragments -> registers (once) ----------------
    bf8 af[2][7];
    #pragma unroll
    for (int m = 0; m < 2; m++) {
        int rr = 32 * (Mt0 + m) + l31;
        bool rv = (rr < NPG);
        float base = rv ? (-two_l * dis[rr]) : 0.f;
        #pragma unroll
        for (int Ks = 0; Ks < 7; Ks++) {
            int k0 = Ks * 16 + 8 * hh;
            unsigned w0 = rv ? Cm[rr * CMW + (k0 >> 2)]     : 0u;
            unsigned w1 = rv ? Cm[rr * CMW + (k0 >> 2) + 1] : 0u;
            #pragma unroll
            for (int j = 0; j < 8; j++) {
                int k = k0 + j;
                unsigned cnt = (((j < 4) ? w0 : w1) >> (8 * (k & 3))) & 255u;
                float v = base * (float)cnt * dis[k];
                if (rv && k == rr) v += cl;
                af[m][Ks][j] = (short)f2bf(v);
            }
        }
    }
    __syncthreads();   // Cm reads done before Tc0 (overlay) is zeroed

    // ---------------- init buf0 (Tc0 + Trm0): zero + x ----------------
    for (int i = tid; i < (SZ_TC + SZ_TRM) / 16; i += 256)
        ((f4*)sm)[i] = (f4){0.f, 0.f, 0.f, 0.f};
    if (tid < HF) pool[tid] = 0.f;
    __syncthreads();
    if (tid < NPG) {
        unsigned short h0 = f2bf(x[(nbase + tid) * 3 + 0]);
        unsigned short h1 = f2bf(x[(nbase + tid) * 3 + 1]);
        unsigned short h2 = f2bf(x[(nbase + tid) * 3 + 2]);
        *(unsigned*)(sm + OFF_TRM0 + (tid * ST) * 2) = (unsigned)h0 | ((unsigned)h1 << 16);
        *(unsigned short*)(sm + OFF_TRM0 + (tid * ST + 2) * 2) = h2;
        *(unsigned short*)(sm + OFF_TC0 + (0 * SAT + tid) * 2) = h0;
        *(unsigned short*)(sm + OFF_TC0 + (1 * SAT + tid) * 2) = h1;
        *(unsigned short*)(sm + OFF_TC0 + (2 * SAT + tid) * 2) = h2;
    }
    __syncthreads();

    // ---------------- 3 ChebConv layers ----------------
    f16v acc[2];
    unsigned prev[2][8], oldr[2][8];   // packed-bf16 T_{s-1}, T_{s-2} at (np, fo) lane positions
    const float* bsv[3] = {b1, b2, b3};

    // prev = x at lane positions (layer 0 T0); later layers carry from epilogue
    #pragma unroll
    for (int m = 0; m < 2; m++) {
        unsigned short tv[16];
        #pragma unroll
        for (int r = 0; r < 16; r++) {
            int np = (Mt0 + m) * 32 + (r & 3) + 8 * (r >> 2) + 4 * hh;
            tv[r] = *(const unsigned short*)(sm + OFF_TRM0 + (np * ST + fo) * 2);
        }
        #pragma unroll
        for (int p = 0; p < 8; p++)
            prev[m][p] = (unsigned)tv[2 * p] | ((unsigned)tv[2 * p + 1] << 16);
    }

    int pc = 0;   // parity of buffer holding current layer's T0 / T_{s-1}
    for (int L = 0; L < 3; L++) {
        const bool l1 = (L == 0);
        const unsigned short* Wl = l1 ? Wt : (Wt + (L == 1 ? 5120 : 25600));
        acc[0] = zerov16();
        acc[1] = zerov16();

        int tS_tc = pc ? OFF_TC1 : OFF_TC0,  tS_tr = pc ? OFF_TRM1 : OFF_TRM0;
        int tD_tc = pc ? OFF_TC0 : OFF_TC1,  tD_tr = pc ? OFF_TRM0 : OFF_TRM1;

        auto TW = [&](int trOff, int k5) {
            const int nKs = l1 ? 1 : 4;
            for (int Ks = 0; Ks < nKs; Ks++) {
                bf8 bw;
                if (l1) bw = *(const bf8*)(Wl + (k5 * 64 + fo) * 16 + 8 * hh);
                else    bw = *(const bf8*)(Wl + (k5 * 64 + fo) * 64 + Ks * 16 + 8 * hh);
                #pragma unroll
                for (int m = 0; m < 2; m++) {
                    bf8 a = *(const bf8*)(sm + trOff +
                              (((Mt0 + m) * 32 + l31) * ST + Ks * 16 + 8 * hh) * 2);
                    acc[m] = __builtin_amdgcn_mfma_f32_32x32x16_bf16(a, bw, acc[m], 0, 0, 0);
                }
            }
        };

        #pragma unroll
        for (int s = 1; s <= 4; s++) {
            // read phase (buf S): LHAT B-frags + TW(s-1) — no sync needed between them
            bf8 bfr[7];
            #pragma unroll
            for (int Ks = 0; Ks < 7; Ks++)
                bfr[Ks] = *(const bf8*)(sm + tS_tc + (fo * SAT + Ks * 16 + 8 * hh) * 2);
            TW(tS_tr, s - 1);
            // compute + write phase (buf D)
            #pragma unroll
            for (int m = 0; m < 2; m++) {
                f16v c = zerov16();
                #pragma unroll
                for (int Ks = 0; Ks < 7; Ks++)
                    c = __builtin_amdgcn_mfma_f32_32x32x16_bf16(af[m][Ks], bfr[Ks], c, 0, 0, 0);
                unsigned short h[16];
                #pragma unroll
                for (int r = 0; r < 16; r++) {
                    float v = c[r];
                    if (s >= 2) {
                        unsigned short o = (unsigned short)
                            ((oldr[m][r >> 1] >> (16 * (r & 1))) & 0xffff);
                        v = 2.f * v - bf2f(o);
                    }
                    h[r] = f2bf(v);
                }
                #pragma unroll
                for (int p = 0; p < 8; p++) {
                    oldr[m][p] = prev[m][p];
                    prev[m][p] = (unsigned)h[2 * p] | ((unsigned)h[2 * p + 1] << 16);
                }
                // Tc writes: node-quads contiguous -> 4x b64
                #pragma unroll
                for (int q4 = 0; q4 < 4; q4++) {
                    int np0 = (Mt0 + m) * 32 + 8 * q4 + 4 * hh;
                    uint2 pk;
                    pk.x = prev[m][2 * q4];
                    pk.y = prev[m][2 * q4 + 1];
                    *(uint2*)(sm + tD_tc + (fo * SAT + np0) * 2) = pk;
                }
                // Trm writes: scalar b16 x16
                #pragma unroll
                for (int r = 0; r < 16; r++) {
                    int np = (Mt0 + m) * 32 + (r & 3) + 8 * (r >> 2) + 4 * hh;
                    *(unsigned short*)(sm + tD_tr + (np * ST + fo) * 2) = h[r];
                }
            }
            __syncthreads();   // T_s visible; all buf-S reads done (next stage writes S)
            int t = tS_tc; tS_tc = tD_tc; tD_tc = t;
            t = tS_tr; tS_tr = tD_tr; tD_tr = t;
        }
        TW(tS_tr, 4);          // T4 is back in parity-pc buffer

        const float bias = bsv[L][fo];
        if (L < 2) {
            // epilogue writes the OPPOSITE buffer (tD) -> no barrier vs TW(4) reads
            #pragma unroll
            for (int m = 0; m < 2; m++) {
                unsigned short h[16];
                #pragma unroll
                for (int r = 0; r < 16; r++) {
                    h[r] = f2bf(fmaxf(acc[m][r] + bias, 0.f));
                    int np = (Mt0 + m) * 32 + (r & 3) + 8 * (r >> 2) + 4 * hh;
                    *(unsigned short*)(sm + tD_tr + (np * ST + fo) * 2) = h[r];
                }
                #pragma unroll
                for (int p = 0; p < 8; p++)
                    prev[m][p] = (unsigned)h[2 * p] | ((unsigned)h[2 * p + 1] << 16);
                #pragma unroll
                for (int q4 = 0; q4 < 4; q4++) {
                    int np0 = (Mt0 + m) * 32 + 8 * q4 + 4 * hh;
                    uint2 pk;
                    pk.x = prev[m][2 * q4];
                    pk.y = prev[m][2 * q4 + 1];
                    *(uint2*)(sm + tD_tc + (fo * SAT + np0) * 2) = pk;
                }
            }
            __syncthreads();   // h visible for next layer's reads
            pc ^= 1;           // next layer's T0 lives in tD parity
        } else {
            float ssum = 0.f;
            #pragma unroll
            for (int m = 0; m < 2; m++) {
                #pragma unroll
                for (int r = 0; r < 16; r++) {
                    int np = (Mt0 + m) * 32 + (r & 3) + 8 * (r >> 2) + 4 * hh;
                    float h = fmaxf(acc[m][r] + bias, 0.f);
                    if (np < NPG) ssum += h;
                }
            }
            ssum += __shfl_xor(ssum, 32, 64);
            if (hh == 0) atomicAdd(&pool[fo], ssum);
            __syncthreads();
        }
    }

    // ---------------- BN + MLP + log_softmax ----------------
    if (tid < HF) {
        float gv = pool[tid] * (1.0f / NPG);
        gv = (gv - bnm[tid]) * rsqrtf(bnv[tid] + 1e-5f) * bng[tid] + bnb[tid];
        gvn[tid] = gv;
    }
    __syncthreads();
    if (tid < 32) {
        float a = fc1b[tid];
        for (int f = 0; f < HF; f++) a += gvn[f] * fc1w[f * 32 + tid];
        zf[tid] = fmaxf(a, 0.f);
    }
    __syncthreads();
    if (tid < 10) {
        float a = fc2b[tid];
        for (int k = 0; k < 32; k++) a += zf[k] * fc2w[k * 10 + tid];
        logits[tid] = a;
    }
    __syncthreads();
    if (tid == 0) {
        float m = logits[0];
        for (int i = 1; i < 10; i++) m = fmaxf(m, logits[i]);
        float s = 0.f;
        for (int i = 0; i < 10; i++) s += expf(logits[i] - m);
        lsep[0] = m + logf(s);
    }
    __syncthreads();
    if (tid < 10) out[g * 10 + tid] = logits[tid] - lsep[0];
}

extern "C" void kernel_launch(void* const* d_in, const int* in_sizes, int n_in,
                              void* d_out, int out_size, void* d_ws, size_t ws_size,
                              hipStream_t stream) {
    const float* x    = (const float*)d_in[0];
    const int*   ei   = (const int*)d_in[1];
    const float* lmax = (const float*)d_in[3];
    const float* W1   = (const float*)d_in[4];
    const float* b1   = (const float*)d_in[5];
    const float* W2   = (const float*)d_in[6];
    const float* b2   = (const float*)d_in[7];
    const float* W3   = (const float*)d_in[8];
    const float* b3   = (const float*)d_in[9];
    const float* bng  = (const float*)d_in[10];
    const float* bnb  = (const float*)d_in[11];
    const float* bnm  = (const float*)d_in[12];
    const float* bnv  = (const float*)d_in[13];
    const float* fc1w = (const float*)d_in[14];
    const float* fc1b = (const float*)d_in[15];
    const float* fc2w = (const float*)d_in[16];
    const float* fc2b = (const float*)d_in[17];

    const int E = in_sizes[1] / 2;
    const int G = in_sizes[3];
    const int epg = E / G;

    unsigned short* Wt = (unsigned short*)d_ws;

    wconv<<<(WT_TOTAL + 255) / 256, 256, 0, stream>>>(W1, W2, W3, Wt);

    hipFuncSetAttribute((const void*)chebpp,
                        hipFuncAttributeMaxDynamicSharedMemorySize, SMEM_BYTES);

    chebpp<<<G, 256, SMEM_BYTES, stream>>>(x, ei, lmax, Wt, b1, b2, b3,
                                           bng, bnb, bnm, bnv, fc1w, fc1b, fc2w, fc2b,
                                           (float*)d_out, E, epg);
}

// Round 10
// 207.181 us; speedup vs baseline: 1.3891x; 1.3891x over previous
//
#include <hip/hip_runtime.h>

#define NPG 100     // nodes per graph
#define HF 64       // hidden width
#define NROW 128    // node rows padded to 4 x 32 tiles
#define ST 72       // Trm row stride (bf16): 64 + 8 pad
#define SAT 136     // Tc row stride (bf16): 128 + 8 pad
#define CMW 28      // count-matrix words per row (112 u8 cols)

typedef float  f4   __attribute__((ext_vector_type(4)));
typedef float  f16v __attribute__((ext_vector_type(16)));
typedef short  bf8  __attribute__((ext_vector_type(8)));

#define SZ_TC  (HF * SAT * 2)         // 17408
#define SZ_TRM (NROW * ST * 2)        // 18432
#define OFF_TC0  0
#define OFF_TRM0 SZ_TC                // 17408
#define OFF_TC1  (OFF_TRM0 + SZ_TRM)  // 35840
#define OFF_TRM1 (OFF_TC1 + SZ_TC)    // 53248
#define OFF_CM   0                    // u8 counts [128][28 u32] = 14336, overlays Tc0 (setup)
#define OFF_MISC (OFF_TRM1 + SZ_TRM)  // 71680
#define SMEM_BYTES (OFF_MISC + 1280)  // 72960 -> LDS allows 2 blocks/CU

// bf16 weight workspace (d_ws), layout Wt[k5][fo][fi]:
//   W1t [5][64][16] @ 0  (fi zero-padded 3->16)
//   W2t [5][64][64] @ 5120
//   W3t [5][64][64] @ 25600
#define WT_TOTAL 46080

__device__ __forceinline__ unsigned short f2bf(float f) {
    unsigned u = __float_as_uint(f);
    u += 0x7fffu + ((u >> 16) & 1u);   // round-to-nearest-even
    return (unsigned short)(u >> 16);
}
__device__ __forceinline__ float bf2f(unsigned short h) {
    return __uint_as_float(((unsigned)h) << 16);
}
__device__ __forceinline__ f16v zerov16() {
    f16v z;
    #pragma unroll
    for (int i = 0; i < 16; i++) z[i] = 0.f;
    return z;
}

__global__ void wconv(const float* __restrict__ W1, const float* __restrict__ W2,
                      const float* __restrict__ W3, unsigned short* __restrict__ ws)
{
    int idx = blockIdx.x * 256 + threadIdx.x;
    if (idx >= WT_TOTAL) return;
    float v;
    if (idx < 5120) {
        int k5 = idx >> 10, rem = idx & 1023, fo = rem >> 4, fi = rem & 15;
        v = (fi < 3) ? W1[(k5 * 3 + fi) * HF + fo] : 0.f;
    } else if (idx < 25600) {
        int j = idx - 5120;
        int k5 = j >> 12, rem = j & 4095, fo = rem >> 6, fi = rem & 63;
        v = W2[(k5 * HF + fi) * HF + fo];
    } else {
        int j = idx - 25600;
        int k5 = j >> 12, rem = j & 4095, fo = rem >> 6, fi = rem & 63;
        v = W3[(k5 * HF + fi) * HF + fo];
    }
    ws[idx] = f2bf(v);
}

// One block per graph, 256 threads = 4 waves, 2 blocks/CU.
// VGPR-cap lore (measured R3/R6/R9): launch_bounds 2nd arg m -> cap ~256/m.
//   m=3 -> 84 (spill), m=2 -> 128 (R9's ~150-live set spilled), m=1 -> 256.
// This kernel: (256,1). Live ~150-170 VGPRs fits; <=256 VGPR still allows
// 2 waves/SIMD -> occupancy stays LDS-limited at 2 blocks/CU.
// A-hat fragments in registers (af[2][7], built once from u8 count matrix).
// PING-PONG dual-orientation T (Tc = T^T for LHAT B b128; Trm for TW A b128):
// stage s reads T_{s-1} from buf S (bfr + TW(s-1) share the read phase), writes
// T_s to buf D, ONE barrier, swap. 14 barriers/block in conv layers (was 24).
// LHAT: C[np][fo] = sum_n Ahat[np][n] * T[n][fo]  (A=af regs, B=Tc rows b128)
// TW:   O[np][fo] += sum_fi T[np][fi] * Wt[fo][fi] (A=Trm rows b128, B=Wt b128)
// C/D: col = lane&31, row = (r&3)+8*(r>>2)+4*(lane>>5)
// Cheb prev/old in packed-bf16 regs; layer T0's prev carried from epilogue regs.
__launch_bounds__(256, 1)
__global__ void chebpp(const float* __restrict__ x, const int* __restrict__ ei,
                       const float* __restrict__ lambda_max,
                       const unsigned short* __restrict__ Wt,
                       const float* __restrict__ b1, const float* __restrict__ b2,
                       const float* __restrict__ b3,
                       const float* __restrict__ bng, const float* __restrict__ bnb,
                       const float* __restrict__ bnm, const float* __restrict__ bnv,
                       const float* __restrict__ fc1w, const float* __restrict__ fc1b,
                       const float* __restrict__ fc2w, const float* __restrict__ fc2b,
                       float* __restrict__ out, int E_total, int epg)
{
    extern __shared__ char sm[];
    const int tid = threadIdx.x;
    const int g = blockIdx.x;
    const int ebase = g * epg, nbase = g * NPG;
    const int wg = tid >> 6, lane = tid & 63;
    const int l31 = lane & 31, hh = lane >> 5;
    const int ht  = wg & 1;          // f-tile: cols 32*ht..+31
    const int Mt0 = (wg >> 1) * 2;   // n'-tile pair base
    const int fo  = ht * 32 + l31;

    unsigned* Cm  = (unsigned*)(sm + OFF_CM);
    float* dis    = (float*)(sm + OFF_MISC);          // 448 B (112 entries)
    float* pool   = (float*)(sm + OFF_MISC + 448);    // 256 B
    float* gvn    = (float*)(sm + OFF_MISC + 704);    // 256 B
    float* zf     = (float*)(sm + OFF_MISC + 960);    // 128 B
    float* logits = (float*)(sm + OFF_MISC + 1088);   // 64 B
    float* lsep   = (float*)(sm + OFF_MISC + 1152);

    const float lam = lambda_max[g];
    const float two_l = 2.0f / lam;
    const float cl = two_l - 1.0f;

    // ---------------- u8 count matrix + dis ----------------
    for (int i = tid; i < (NROW * CMW) / 4; i += 256)
        ((f4*)Cm)[i] = (f4){0.f, 0.f, 0.f, 0.f};
    __syncthreads();
    for (int e = tid; e < epg; e += 256) {
        int r = ei[ebase + e] - nbase;
        int c = ei[E_total + ebase + e] - nbase;
        atomicAdd(&Cm[r * CMW + (c >> 2)], 1u << (8 * (c & 3)));
    }
    __syncthreads();
    if (tid < 112) {
        float dv = 0.f;
        if (tid < NPG) {
            unsigned s = 0;
            #pragma unroll
            for (int w = 0; w < CMW; w++) {
                unsigned u = Cm[tid * CMW + w];
                s += (u & 255) + ((u >> 8) & 255) + ((u >> 16) & 255) + (u >> 24);
            }
            dv = s > 0 ? rsqrtf((float)s) : 0.f;
        }
        dis[tid] = dv;
    }
    __syncthreads();

    // ---------------- A-hat fragments -> registers (once) ----------------
    bf8 af[2][7];
    #pragma unroll
    for (int m = 0; m < 2; m++) {
        int rr = 32 * (Mt0 + m) + l31;
        bool rv = (rr < NPG);
        float base = rv ? (-two_l * dis[rr]) : 0.f;
        #pragma unroll
        for (int Ks = 0; Ks < 7; Ks++) {
            int k0 = Ks * 16 + 8 * hh;
            unsigned w0 = rv ? Cm[rr * CMW + (k0 >> 2)]     : 0u;
            unsigned w1 = rv ? Cm[rr * CMW + (k0 >> 2) + 1] : 0u;
            #pragma unroll
            for (int j = 0; j < 8; j++) {
                int k = k0 + j;
                unsigned cnt = (((j < 4) ? w0 : w1) >> (8 * (k & 3))) & 255u;
                float v = base * (float)cnt * dis[k];
                if (rv && k == rr) v += cl;
                af[m][Ks][j] = (short)f2bf(v);
            }
        }
    }
    __syncthreads();   // Cm reads done before Tc0 (overlay) is zeroed

    // ---------------- init buf0 (Tc0 + Trm0): zero + x ----------------
    for (int i = tid; i < (SZ_TC + SZ_TRM) / 16; i += 256)
        ((f4*)sm)[i] = (f4){0.f, 0.f, 0.f, 0.f};
    if (tid < HF) pool[tid] = 0.f;
    __syncthreads();
    if (tid < NPG) {
        unsigned short h0 = f2bf(x[(nbase + tid) * 3 + 0]);
        unsigned short h1 = f2bf(x[(nbase + tid) * 3 + 1]);
        unsigned short h2 = f2bf(x[(nbase + tid) * 3 + 2]);
        *(unsigned*)(sm + OFF_TRM0 + (tid * ST) * 2) = (unsigned)h0 | ((unsigned)h1 << 16);
        *(unsigned short*)(sm + OFF_TRM0 + (tid * ST + 2) * 2) = h2;
        *(unsigned short*)(sm + OFF_TC0 + (0 * SAT + tid) * 2) = h0;
        *(unsigned short*)(sm + OFF_TC0 + (1 * SAT + tid) * 2) = h1;
        *(unsigned short*)(sm + OFF_TC0 + (2 * SAT + tid) * 2) = h2;
    }
    __syncthreads();

    // ---------------- 3 ChebConv layers ----------------
    f16v acc[2];
    unsigned prev[2][8], oldr[2][8];   // packed-bf16 T_{s-1}, T_{s-2} at (np, fo) lane positions
    const float* bsv[3] = {b1, b2, b3};

    // prev = x at lane positions (layer 0 T0); later layers carry from epilogue
    #pragma unroll
    for (int m = 0; m < 2; m++) {
        unsigned short tv[16];
        #pragma unroll
        for (int r = 0; r < 16; r++) {
            int np = (Mt0 + m) * 32 + (r & 3) + 8 * (r >> 2) + 4 * hh;
            tv[r] = *(const unsigned short*)(sm + OFF_TRM0 + (np * ST + fo) * 2);
        }
        #pragma unroll
        for (int p = 0; p < 8; p++)
            prev[m][p] = (unsigned)tv[2 * p] | ((unsigned)tv[2 * p + 1] << 16);
    }

    int pc = 0;   // parity of buffer holding current layer's T0 / T_{s-1}
    for (int L = 0; L < 3; L++) {
        const bool l1 = (L == 0);
        const unsigned short* Wl = l1 ? Wt : (Wt + (L == 1 ? 5120 : 25600));
        acc[0] = zerov16();
        acc[1] = zerov16();

        int tS_tc = pc ? OFF_TC1 : OFF_TC0,  tS_tr = pc ? OFF_TRM1 : OFF_TRM0;
        int tD_tc = pc ? OFF_TC0 : OFF_TC1,  tD_tr = pc ? OFF_TRM0 : OFF_TRM1;

        auto TW = [&](int trOff, int k5) {
            const int nKs = l1 ? 1 : 4;
            for (int Ks = 0; Ks < nKs; Ks++) {
                bf8 bw;
                if (l1) bw = *(const bf8*)(Wl + (k5 * 64 + fo) * 16 + 8 * hh);
                else    bw = *(const bf8*)(Wl + (k5 * 64 + fo) * 64 + Ks * 16 + 8 * hh);
                #pragma unroll
                for (int m = 0; m < 2; m++) {
                    bf8 a = *(const bf8*)(sm + trOff +
                              (((Mt0 + m) * 32 + l31) * ST + Ks * 16 + 8 * hh) * 2);
                    acc[m] = __builtin_amdgcn_mfma_f32_32x32x16_bf16(a, bw, acc[m], 0, 0, 0);
                }
            }
        };

        #pragma unroll
        for (int s = 1; s <= 4; s++) {
            // read phase (buf S): LHAT B-frags + TW(s-1) — no sync needed between them
            bf8 bfr[7];
            #pragma unroll
            for (int Ks = 0; Ks < 7; Ks++)
                bfr[Ks] = *(const bf8*)(sm + tS_tc + (fo * SAT + Ks * 16 + 8 * hh) * 2);
            TW(tS_tr, s - 1);
            // compute + write phase (buf D)
            #pragma unroll
            for (int m = 0; m < 2; m++) {
                f16v c = zerov16();
                #pragma unroll
                for (int Ks = 0; Ks < 7; Ks++)
                    c = __builtin_amdgcn_mfma_f32_32x32x16_bf16(af[m][Ks], bfr[Ks], c, 0, 0, 0);
                unsigned short h[16];
                #pragma unroll
                for (int r = 0; r < 16; r++) {
                    float v = c[r];
                    if (s >= 2) {
                        unsigned short o = (unsigned short)
                            ((oldr[m][r >> 1] >> (16 * (r & 1))) & 0xffff);
                        v = 2.f * v - bf2f(o);
                    }
                    h[r] = f2bf(v);
                }
                #pragma unroll
                for (int p = 0; p < 8; p++) {
                    oldr[m][p] = prev[m][p];
                    prev[m][p] = (unsigned)h[2 * p] | ((unsigned)h[2 * p + 1] << 16);
                }
                // Tc writes: node-quads contiguous -> 4x b64
                #pragma unroll
                for (int q4 = 0; q4 < 4; q4++) {
                    int np0 = (Mt0 + m) * 32 + 8 * q4 + 4 * hh;
                    uint2 pk;
                    pk.x = prev[m][2 * q4];
                    pk.y = prev[m][2 * q4 + 1];
                    *(uint2*)(sm + tD_tc + (fo * SAT + np0) * 2) = pk;
                }
                // Trm writes: scalar b16 x16
                #pragma unroll
                for (int r = 0; r < 16; r++) {
                    int np = (Mt0 + m) * 32 + (r & 3) + 8 * (r >> 2) + 4 * hh;
                    *(unsigned short*)(sm + tD_tr + (np * ST + fo) * 2) = h[r];
                }
            }
            __syncthreads();   // T_s visible; all buf-S reads done (next stage writes S)
            int t = tS_tc; tS_tc = tD_tc; tD_tc = t;
            t = tS_tr; tS_tr = tD_tr; tD_tr = t;
        }
        TW(tS_tr, 4);          // T4 is back in parity-pc buffer

        const float bias = bsv[L][fo];
        if (L < 2) {
            // epilogue writes the OPPOSITE buffer (tD) -> no barrier vs TW(4) reads
            #pragma unroll
            for (int m = 0; m < 2; m++) {
                unsigned short h[16];
                #pragma unroll
                for (int r = 0; r < 16; r++) {
                    h[r] = f2bf(fmaxf(acc[m][r] + bias, 0.f));
                    int np = (Mt0 + m) * 32 + (r & 3) + 8 * (r >> 2) + 4 * hh;
                    *(unsigned short*)(sm + tD_tr + (np * ST + fo) * 2) = h[r];
                }
                #pragma unroll
                for (int p = 0; p < 8; p++)
                    prev[m][p] = (unsigned)h[2 * p] | ((unsigned)h[2 * p + 1] << 16);
                #pragma unroll
                for (int q4 = 0; q4 < 4; q4++) {
                    int np0 = (Mt0 + m) * 32 + 8 * q4 + 4 * hh;
                    uint2 pk;
                    pk.x = prev[m][2 * q4];
                    pk.y = prev[m][2 * q4 + 1];
                    *(uint2*)(sm + tD_tc + (fo * SAT + np0) * 2) = pk;
                }
            }
            __syncthreads();   // h visible for next layer's reads
            pc ^= 1;           // next layer's T0 lives in tD parity
        } else {
            float ssum = 0.f;
            #pragma unroll
            for (int m = 0; m < 2; m++) {
                #pragma unroll
                for (int r = 0; r < 16; r++) {
                    int np = (Mt0 + m) * 32 + (r & 3) + 8 * (r >> 2) + 4 * hh;
                    float h = fmaxf(acc[m][r] + bias, 0.f);
                    if (np < NPG) ssum += h;
                }
            }
            ssum += __shfl_xor(ssum, 32, 64);
            if (hh == 0) atomicAdd(&pool[fo], ssum);
            __syncthreads();
        }
    }

    // ---------------- BN + MLP + log_softmax ----------------
    if (tid < HF) {
        float gv = pool[tid] * (1.0f / NPG);
        gv = (gv - bnm[tid]) * rsqrtf(bnv[tid] + 1e-5f) * bng[tid] + bnb[tid];
        gvn[tid] = gv;
    }
    __syncthreads();
    if (tid < 32) {
        float a = fc1b[tid];
        for (int f = 0; f < HF; f++) a += gvn[f] * fc1w[f * 32 + tid];
        zf[tid] = fmaxf(a, 0.f);
    }
    __syncthreads();
    if (tid < 10) {
        float a = fc2b[tid];
        for (int k = 0; k < 32; k++) a += zf[k] * fc2w[k * 10 + tid];
        logits[tid] = a;
    }
    __syncthreads();
    if (tid == 0) {
        float m = logits[0];
        for (int i = 1; i < 10; i++) m = fmaxf(m, logits[i]);
        float s = 0.f;
        for (int i = 0; i < 10; i++) s += expf(logits[i] - m);
        lsep[0] = m + logf(s);
    }
    __syncthreads();
    if (tid < 10) out[g * 10 + tid] = logits[tid] - lsep[0];
}

extern "C" void kernel_launch(void* const* d_in, const int* in_sizes, int n_in,
                              void* d_out, int out_size, void* d_ws, size_t ws_size,
                              hipStream_t stream) {
    const float* x    = (const float*)d_in[0];
    const int*   ei   = (const int*)d_in[1];
    const float* lmax = (const float*)d_in[3];
    const float* W1   = (const float*)d_in[4];
    const float* b1   = (const float*)d_in[5];
    const float* W2   = (const float*)d_in[6];
    const float* b2   = (const float*)d_in[7];
    const float* W3   = (const float*)d_in[8];
    const float* b3   = (const float*)d_in[9];
    const float* bng  = (const float*)d_in[10];
    const float* bnb  = (const float*)d_in[11];
    const float* bnm  = (const float*)d_in[12];
    const float* bnv  = (const float*)d_in[13];
    const float* fc1w = (const float*)d_in[14];
    const float* fc1b = (const float*)d_in[15];
    const float* fc2w = (const float*)d_in[16];
    const float* fc2b = (const float*)d_in[17];

    const int E = in_sizes[1] / 2;
    const int G = in_sizes[3];
    const int epg = E / G;

    unsigned short* Wt = (unsigned short*)d_ws;

    wconv<<<(WT_TOTAL + 255) / 256, 256, 0, stream>>>(W1, W2, W3, Wt);

    hipFuncSetAttribute((const void*)chebpp,
                        hipFuncAttributeMaxDynamicSharedMemorySize, SMEM_BYTES);

    chebpp<<<G, 256, SMEM_BYTES, stream>>>(x, ei, lmax, Wt, b1, b2, b3,
                                           bng, bnb, bnm, bnv, fc1w, fc1b, fc2w, fc2b,
                                           (float*)d_out, E, epg);
}

// Round 11
// 177.792 us; speedup vs baseline: 1.6188x; 1.1653x over previous
//
#include <hip/hip_runtime.h>
#include <hip/hip_bf16.h>

#define NPG 100     // nodes per graph
#define HF 64       // hidden width
#define NROW 128    // node rows padded to 4 x 32 tiles
#define ST 72       // Trm row stride (bf16): 64 + 8 pad
#define SAT 136     // Tc row stride (bf16): 128 + 8 pad
#define CMW 28      // count-matrix words per row (112 u8 cols)

typedef float  f4   __attribute__((ext_vector_type(4)));
typedef float  f16v __attribute__((ext_vector_type(16)));
typedef short  bf8  __attribute__((ext_vector_type(8)));

#define SZ_TC  (HF * SAT * 2)         // 17408
#define SZ_TRM (NROW * ST * 2)        // 18432
#define OFF_TC  0
#define OFF_TRM SZ_TC                 // 17408
#define OFF_CM  0                     // u8 counts [128][28 u32] = 14336, overlays Tc (setup)
#define OFF_MISC (OFF_TRM + SZ_TRM)   // 35840
#define SMEM_BYTES (OFF_MISC + 1280)  // 37120

// bf16 weight workspace (d_ws), layout Wt[k5][fo][fi]:
//   W1t [5][64][16] @ 0  (fi zero-padded 3->16)
//   W2t [5][64][64] @ 5120
//   W3t [5][64][64] @ 25600
#define WT_TOTAL 46080

__device__ __forceinline__ unsigned short f2bf(float f) {
    unsigned u = __float_as_uint(f);
    u += 0x7fffu + ((u >> 16) & 1u);   // round-to-nearest-even
    return (unsigned short)(u >> 16);
}
// packed 2xf32 -> packed bf16x2 (v_cvt_pk_bf16_f32 on gfx950, RNE — same as f2bf)
__device__ __forceinline__ unsigned pk2bf(float a, float b) {
    float2 f2; f2.x = a; f2.y = b;
    __hip_bfloat162 h2 = __float22bfloat162_rn(f2);
    return *reinterpret_cast<unsigned*>(&h2);
}
__device__ __forceinline__ f16v zerov16() {
    f16v z;
    #pragma unroll
    for (int i = 0; i < 16; i++) z[i] = 0.f;
    return z;
}

__global__ void wconv(const float* __restrict__ W1, const float* __restrict__ W2,
                      const float* __restrict__ W3, unsigned short* __restrict__ ws)
{
    int idx = blockIdx.x * 256 + threadIdx.x;
    if (idx >= WT_TOTAL) return;
    float v;
    if (idx < 5120) {
        int k5 = idx >> 10, rem = idx & 1023, fo = rem >> 4, fi = rem & 15;
        v = (fi < 3) ? W1[(k5 * 3 + fi) * HF + fo] : 0.f;
    } else if (idx < 25600) {
        int j = idx - 5120;
        int k5 = j >> 12, rem = j & 4095, fo = rem >> 6, fi = rem & 63;
        v = W2[(k5 * HF + fi) * HF + fo];
    } else {
        int j = idx - 25600;
        int k5 = j >> 12, rem = j & 4095, fo = rem >> 6, fi = rem & 63;
        v = W3[(k5 * HF + fi) * HF + fo];
    }
    ws[idx] = f2bf(v);
}

// One block per graph, 256 threads = 4 waves. R8 structure (best: 87 us) +
// packed bf16 converts + dead-code elim. VGPR-cap lore (R3/R6/R9/R10):
// launch_bounds min-waves m -> VGPR cap ~256/m; and >128 live VGPRs halves
// resident waves (R10: 188 VGPR -> 1 block/CU). Keep (256,2), live set <=128.
// A-hat fragments in registers (af[2][7], built once from u8 count matrix).
// Single in-place dual-orientation T: Tc = T^T (LHAT B b128), Trm (TW A b128).
// LHAT: C[np][fo] = sum_n Ahat[np][n] * T[n][fo]  (A=af regs, B=Tc rows b128)
// TW:   O[np][fo] += sum_fi T[np][fi] * Wt[fo][fi] (A=Trm rows b128, B=Wt b128)
// C/D: col = lane&31, row = (r&3)+8*(r>>2)+4*(lane>>5)
// Cheb prev/old in packed-bf16 regs (carried across layers via epilogue regs);
// cheb update done in packed domain (unpack = 1 shift/op, pack = 1 cvt_pk/2).
__launch_bounds__(256, 2)
__global__ void chebpk(const float* __restrict__ x, const int* __restrict__ ei,
                       const float* __restrict__ lambda_max,
                       const unsigned short* __restrict__ Wt,
                       const float* __restrict__ b1, const float* __restrict__ b2,
                       const float* __restrict__ b3,
                       const float* __restrict__ bng, const float* __restrict__ bnb,
                       const float* __restrict__ bnm, const float* __restrict__ bnv,
                       const float* __restrict__ fc1w, const float* __restrict__ fc1b,
                       const float* __restrict__ fc2w, const float* __restrict__ fc2b,
                       float* __restrict__ out, int E_total, int epg)
{
    extern __shared__ char sm[];
    const int tid = threadIdx.x;
    const int g = blockIdx.x;
    const int ebase = g * epg, nbase = g * NPG;
    const int wg = tid >> 6, lane = tid & 63;
    const int l31 = lane & 31, hh = lane >> 5;
    const int ht  = wg & 1;          // f-tile: cols 32*ht..+31
    const int Mt0 = (wg >> 1) * 2;   // n'-tile pair base
    const int fo  = ht * 32 + l31;

    unsigned* Cm  = (unsigned*)(sm + OFF_CM);
    float* dis    = (float*)(sm + OFF_MISC);          // 448 B (112 entries)
    float* pool   = (float*)(sm + OFF_MISC + 448);    // 256 B
    float* gvn    = (float*)(sm + OFF_MISC + 704);    // 256 B
    float* zf     = (float*)(sm + OFF_MISC + 960);    // 128 B
    float* logits = (float*)(sm + OFF_MISC + 1088);   // 64 B
    float* lsep   = (float*)(sm + OFF_MISC + 1152);

    const float lam = lambda_max[g];
    const float two_l = 2.0f / lam;
    const float cl = two_l - 1.0f;

    // ---------------- u8 count matrix + dis ----------------
    for (int i = tid; i < (NROW * CMW) / 4; i += 256)
        ((f4*)Cm)[i] = (f4){0.f, 0.f, 0.f, 0.f};
    __syncthreads();
    for (int e = tid; e < epg; e += 256) {
        int r = ei[ebase + e] - nbase;
        int c = ei[E_total + ebase + e] - nbase;
        atomicAdd(&Cm[r * CMW + (c >> 2)], 1u << (8 * (c & 3)));
    }
    __syncthreads();
    if (tid < 112) {
        float dv = 0.f;
        if (tid < NPG) {
            unsigned s = 0;
            #pragma unroll
            for (int w = 0; w < CMW; w++) {
                unsigned u = Cm[tid * CMW + w];
                s += (u & 255) + ((u >> 8) & 255) + ((u >> 16) & 255) + (u >> 24);
            }
            dv = s > 0 ? rsqrtf((float)s) : 0.f;
        }
        dis[tid] = dv;
    }
    __syncthreads();

    // ---------------- A-hat fragments -> registers (once) ----------------
    bf8 af[2][7];
    #pragma unroll
    for (int m = 0; m < 2; m++) {
        int rr = 32 * (Mt0 + m) + l31;
        bool rv = (rr < NPG);
        float base = rv ? (-two_l * dis[rr]) : 0.f;
        #pragma unroll
        for (int Ks = 0; Ks < 7; Ks++) {
            int k0 = Ks * 16 + 8 * hh;
            unsigned w0 = rv ? Cm[rr * CMW + (k0 >> 2)]     : 0u;
            unsigned w1 = rv ? Cm[rr * CMW + (k0 >> 2) + 1] : 0u;
            unsigned up[4];
            #pragma unroll
            for (int jj = 0; jj < 4; jj++) {
                int ka = k0 + 2 * jj, kb = ka + 1;
                unsigned wa = (jj < 2) ? w0 : w1;
                float va = base * (float)((wa >> (8 * (ka & 3))) & 255u) * dis[ka];
                float vb = base * (float)((wa >> (8 * (kb & 3))) & 255u) * dis[kb];
                if (rv && ka == rr) va += cl;
                if (rv && kb == rr) vb += cl;
                up[jj] = pk2bf(va, vb);
            }
            af[m][Ks] = *reinterpret_cast<bf8*>(up);
        }
    }
    __syncthreads();   // Cm reads done before Tc (overlay) is zeroed

    // ---------------- init Tc + Trm: zero + x ----------------
    for (int i = tid; i < (SZ_TC + SZ_TRM) / 16; i += 256)
        ((f4*)sm)[i] = (f4){0.f, 0.f, 0.f, 0.f};
    if (tid < HF) pool[tid] = 0.f;
    __syncthreads();
    if (tid < NPG) {
        unsigned short h0 = f2bf(x[(nbase + tid) * 3 + 0]);
        unsigned short h1 = f2bf(x[(nbase + tid) * 3 + 1]);
        unsigned short h2 = f2bf(x[(nbase + tid) * 3 + 2]);
        *(unsigned*)(sm + OFF_TRM + (tid * ST) * 2) = (unsigned)h0 | ((unsigned)h1 << 16);
        *(unsigned short*)(sm + OFF_TRM + (tid * ST + 2) * 2) = h2;
        *(unsigned short*)(sm + OFF_TC + (0 * SAT + tid) * 2) = h0;
        *(unsigned short*)(sm + OFF_TC + (1 * SAT + tid) * 2) = h1;
        *(unsigned short*)(sm + OFF_TC + (2 * SAT + tid) * 2) = h2;
    }
    __syncthreads();

    // ---------------- 3 ChebConv layers ----------------
    f16v acc[2];
    unsigned prev[2][8], oldr[2][8];   // packed-bf16 T_{s-1}, T_{s-2} at (np, fo) lane positions
    const float* bsv[3] = {b1, b2, b3};

    // prev = x (layer 0 T0) at C-layout lane positions; later layers carry from epilogue
    #pragma unroll
    for (int m = 0; m < 2; m++) {
        unsigned short tv[16];
        #pragma unroll
        for (int r = 0; r < 16; r++) {
            int np = (Mt0 + m) * 32 + (r & 3) + 8 * (r >> 2) + 4 * hh;
            tv[r] = *(const unsigned short*)(sm + OFF_TRM + (np * ST + fo) * 2);
        }
        #pragma unroll
        for (int p = 0; p < 8; p++)
            prev[m][p] = (unsigned)tv[2 * p] | ((unsigned)tv[2 * p + 1] << 16);
    }

    for (int L = 0; L < 3; L++) {
        const bool l1 = (L == 0);
        const unsigned short* Wl = l1 ? Wt : (Wt + (L == 1 ? 5120 : 25600));
        acc[0] = zerov16();
        acc[1] = zerov16();

        auto TW = [&](int k5) {
            const int nKs = l1 ? 1 : 4;
            for (int Ks = 0; Ks < nKs; Ks++) {
                bf8 bw;
                if (l1) bw = *(const bf8*)(Wl + (k5 * 64 + fo) * 16 + 8 * hh);
                else    bw = *(const bf8*)(Wl + (k5 * 64 + fo) * 64 + Ks * 16 + 8 * hh);
                #pragma unroll
                for (int m = 0; m < 2; m++) {
                    bf8 a = *(const bf8*)(sm + OFF_TRM +
                              (((Mt0 + m) * 32 + l31) * ST + Ks * 16 + 8 * hh) * 2);
                    acc[m] = __builtin_amdgcn_mfma_f32_32x32x16_bf16(a, bw, acc[m], 0, 0, 0);
                }
            }
        };

        TW(0);
        #pragma unroll
        for (int s = 1; s <= 4; s++) {
            // B-frags: Tc rows (this lane's fo column set), b128
            bf8 bfr[7];
            #pragma unroll
            for (int Ks = 0; Ks < 7; Ks++)
                bfr[Ks] = *(const bf8*)(sm + OFF_TC + (fo * SAT + Ks * 16 + 8 * hh) * 2);
            __syncthreads();   // all T reads (TW(s-1), bfr) done before in-place writes
            #pragma unroll
            for (int m = 0; m < 2; m++) {
                f16v c = zerov16();
                #pragma unroll
                for (int Ks = 0; Ks < 7; Ks++)
                    c = __builtin_amdgcn_mfma_f32_32x32x16_bf16(af[m][Ks], bfr[Ks], c, 0, 0, 0);
                unsigned hp[8];
                #pragma unroll
                for (int p = 0; p < 8; p++) {
                    float c0 = c[2 * p], c1 = c[2 * p + 1];
                    if (s >= 2) {   // packed-domain cheb: unpack = 1 op each
                        float olo = __uint_as_float(oldr[m][p] << 16);
                        float ohi = __uint_as_float(oldr[m][p] & 0xffff0000u);
                        c0 = 2.f * c0 - olo;
                        c1 = 2.f * c1 - ohi;
                    }
                    hp[p] = pk2bf(c0, c1);
                    if (s < 4) {   // T4's prev/oldr are dead
                        oldr[m][p] = prev[m][p];
                        prev[m][p] = hp[p];
                    }
                }
                if (s < 4) {       // T4's Tc is never read (epilogue rewrites Tc fully)
                    #pragma unroll
                    for (int q4 = 0; q4 < 4; q4++) {
                        int np0 = (Mt0 + m) * 32 + 8 * q4 + 4 * hh;
                        uint2 pk;
                        pk.x = hp[2 * q4];
                        pk.y = hp[2 * q4 + 1];
                        *(uint2*)(sm + OFF_TC + (fo * SAT + np0) * 2) = pk;
                    }
                }
                // Trm writes: scalar b16 x16 (b16 / b16_d16_hi from packed regs)
                #pragma unroll
                for (int r = 0; r < 16; r++) {
                    int np = (Mt0 + m) * 32 + (r & 3) + 8 * (r >> 2) + 4 * hh;
                    unsigned short hv = (r & 1) ? (unsigned short)(hp[r >> 1] >> 16)
                                                : (unsigned short)(hp[r >> 1] & 0xffffu);
                    *(unsigned short*)(sm + OFF_TRM + (np * ST + fo) * 2) = hv;
                }
            }
            __syncthreads();   // writes visible before TW(s)
            TW(s);
        }
        __syncthreads();       // TW(4) reads done before epilogue writes

        const float bias = bsv[L][fo];
        if (L < 2) {
            #pragma unroll
            for (int m = 0; m < 2; m++) {
                unsigned hp[8];
                #pragma unroll
                for (int p = 0; p < 8; p++) {
                    float v0 = fmaxf(acc[m][2 * p]     + bias, 0.f);
                    float v1 = fmaxf(acc[m][2 * p + 1] + bias, 0.f);
                    hp[p] = pk2bf(v0, v1);
                    prev[m][p] = hp[p];   // next layer's T0 carried in regs
                }
                #pragma unroll
                for (int q4 = 0; q4 < 4; q4++) {
                    int np0 = (Mt0 + m) * 32 + 8 * q4 + 4 * hh;
                    uint2 pk;
                    pk.x = hp[2 * q4];
                    pk.y = hp[2 * q4 + 1];
                    *(uint2*)(sm + OFF_TC + (fo * SAT + np0) * 2) = pk;
                }
                #pragma unroll
                for (int r = 0; r < 16; r++) {
                    int np = (Mt0 + m) * 32 + (r & 3) + 8 * (r >> 2) + 4 * hh;
                    unsigned short hv = (r & 1) ? (unsigned short)(hp[r >> 1] >> 16)
                                                : (unsigned short)(hp[r >> 1] & 0xffffu);
                    *(unsigned short*)(sm + OFF_TRM + (np * ST + fo) * 2) = hv;
                }
            }
            __syncthreads();
        } else {
            float ssum = 0.f;
            #pragma unroll
            for (int m = 0; m < 2; m++) {
                #pragma unroll
                for (int r = 0; r < 16; r++) {
                    int np = (Mt0 + m) * 32 + (r & 3) + 8 * (r >> 2) + 4 * hh;
                    float h = fmaxf(acc[m][r] + bias, 0.f);
                    if (np < NPG) ssum += h;
                }
            }
            ssum += __shfl_xor(ssum, 32, 64);
            if (hh == 0) atomicAdd(&pool[fo], ssum);
            __syncthreads();
        }
    }

    // ---------------- BN + MLP + log_softmax ----------------
    if (tid < HF) {
        float gv = pool[tid] * (1.0f / NPG);
        gv = (gv - bnm[tid]) * rsqrtf(bnv[tid] + 1e-5f) * bng[tid] + bnb[tid];
        gvn[tid] = gv;
    }
    __syncthreads();
    if (tid < 32) {
        float a = fc1b[tid];
        for (int f = 0; f < HF; f++) a += gvn[f] * fc1w[f * 32 + tid];
        zf[tid] = fmaxf(a, 0.f);
    }
    __syncthreads();
    if (tid < 10) {
        float a = fc2b[tid];
        for (int k = 0; k < 32; k++) a += zf[k] * fc2w[k * 10 + tid];
        logits[tid] = a;
    }
    __syncthreads();
    if (tid == 0) {
        float m = logits[0];
        for (int i = 1; i < 10; i++) m = fmaxf(m, logits[i]);
        float s = 0.f;
        for (int i = 0; i < 10; i++) s += expf(logits[i] - m);
        lsep[0] = m + logf(s);
    }
    __syncthreads();
    if (tid < 10) out[g * 10 + tid] = logits[tid] - lsep[0];
}

extern "C" void kernel_launch(void* const* d_in, const int* in_sizes, int n_in,
                              void* d_out, int out_size, void* d_ws, size_t ws_size,
                              hipStream_t stream) {
    const float* x    = (const float*)d_in[0];
    const int*   ei   = (const int*)d_in[1];
    const float* lmax = (const float*)d_in[3];
    const float* W1   = (const float*)d_in[4];
    const float* b1   = (const float*)d_in[5];
    const float* W2   = (const float*)d_in[6];
    const float* b2   = (const float*)d_in[7];
    const float* W3   = (const float*)d_in[8];
    const float* b3   = (const float*)d_in[9];
    const float* bng  = (const float*)d_in[10];
    const float* bnb  = (const float*)d_in[11];
    const float* bnm  = (const float*)d_in[12];
    const float* bnv  = (const float*)d_in[13];
    const float* fc1w = (const float*)d_in[14];
    const float* fc1b = (const float*)d_in[15];
    const float* fc2w = (const float*)d_in[16];
    const float* fc2b = (const float*)d_in[17];

    const int E = in_sizes[1] / 2;
    const int G = in_sizes[3];
    const int epg = E / G;

    unsigned short* Wt = (unsigned short*)d_ws;

    wconv<<<(WT_TOTAL + 255) / 256, 256, 0, stream>>>(W1, W2, W3, Wt);

    hipFuncSetAttribute((const void*)chebpk,
                        hipFuncAttributeMaxDynamicSharedMemorySize, SMEM_BYTES);

    chebpk<<<G, 256, SMEM_BYTES, stream>>>(x, ei, lmax, Wt, b1, b2, b3,
                                           bng, bnb, bnm, bnv, fc1w, fc1b, fc2w, fc2b,
                                           (float*)d_out, E, epg);
}